// Round 1
// baseline (39.496 us; speedup 1.0000x reference)
//
#include <hip/hip_runtime.h>
#include <hip/hip_bf16.h>

typedef __attribute__((ext_vector_type(8))) short short8;
typedef __attribute__((ext_vector_type(4))) float f32x4;

constexpr int Tt = 8192, Kd = 1024, Nd = 1024, Gn = 8;
constexpr int BM = 128, BN = 128, BK = 64;
constexpr int NKT = Kd / BK; // 16 K-steps

static __device__ __forceinline__ short f2bf(float x) {
    __hip_bfloat16 b = __float2bfloat16(x);
    return *reinterpret_cast<short*>(&b);
}

__global__ __launch_bounds__(256, 2)
void grouped_gemm_kernel(const float* __restrict__ H,
                         const float* __restrict__ W,
                         const int* __restrict__ counts,
                         float* __restrict__ out)
{
    // double-buffered LDS tiles, bf16, [row][8 chunks of 8 elems], XOR-swizzled
    __shared__ __align__(16) short As[2][BM * BK];
    __shared__ __align__(16) short Bs[2][BN * BK];

    const int tid = threadIdx.x;
    const int bid = blockIdx.x;
    // bijective XCD swizzle (512 % 8 == 0)
    const int wg = (bid & 7) * 64 + (bid >> 3);
    const int mt = wg >> 3, nt = wg & 7;
    const int row0 = mt * BM, col0 = nt * BN;

    // expert id for this row tile (counts are multiples of BM -> no straddle)
    int g = 0;
    {
        int c = 0;
        for (int i = 0; i < Gn; ++i) { c += counts[i]; if (row0 >= c) g = i + 1; }
    }
    const float* __restrict__ Wg = W + (size_t)g * Kd * Nd;

    const int wid = tid >> 6, lane = tid & 63;
    const int wm = wid >> 1, wn = wid & 1;   // 2x2 wave grid, each wave 64x64
    const int l15 = lane & 15, l4 = lane >> 4;

    f32x4 acc[4][4];
#pragma unroll
    for (int i = 0; i < 4; ++i)
#pragma unroll
        for (int j = 0; j < 4; ++j) acc[i][j] = (f32x4)0.0f;

    // staging registers for the next tile
    f32x4 a_reg[4][2];
    float b_reg[4][8];

    auto issue_loads = [&](int kt) {
        const int kbase = kt * BK;
#pragma unroll
        for (int i = 0; i < 4; ++i) {
            const int idx = i * 256 + tid;
            const int m = idx >> 3, kc = idx & 7;     // A chunk (m, kc): 8 k-elems
            const float* p = H + (size_t)(row0 + m) * Kd + kbase + kc * 8;
            a_reg[i][0] = *(const f32x4*)p;
            a_reg[i][1] = *(const f32x4*)(p + 4);
        }
#pragma unroll
        for (int i = 0; i < 4; ++i) {
            const int idx = i * 256 + tid;
            const int kc = idx >> 7, n = idx & 127;   // B chunk (n, kc)
            const float* p = Wg + (size_t)(kbase + kc * 8) * Nd + col0 + n;
#pragma unroll
            for (int j = 0; j < 8; ++j) b_reg[i][j] = p[(size_t)j * Nd];
        }
    };

    auto write_stage = [&](int buf) {
#pragma unroll
        for (int i = 0; i < 4; ++i) {
            const int idx = i * 256 + tid;
            const int m = idx >> 3, kc = idx & 7;
            short8 v;
#pragma unroll
            for (int j = 0; j < 4; ++j) v[j] = f2bf(a_reg[i][0][j]);
#pragma unroll
            for (int j = 0; j < 4; ++j) v[4 + j] = f2bf(a_reg[i][1][j]);
            *(short8*)&As[buf][m * BK + ((kc ^ (m & 7)) << 3)] = v;
        }
#pragma unroll
        for (int i = 0; i < 4; ++i) {
            const int idx = i * 256 + tid;
            const int kc = idx >> 7, n = idx & 127;
            short8 v;
#pragma unroll
            for (int j = 0; j < 8; ++j) v[j] = f2bf(b_reg[i][j]);
            *(short8*)&Bs[buf][n * BK + ((kc ^ (n & 7)) << 3)] = v;
        }
    };

    auto compute = [&](int buf) {
#pragma unroll
        for (int ks = 0; ks < 2; ++ks) {         // two K=32 slices per BK=64
            short8 af[4], bfr[4];
#pragma unroll
            for (int mi = 0; mi < 4; ++mi) {
                const int r = wm * 64 + mi * 16 + l15;
                const int c = (ks * 4 + l4) ^ (r & 7);
                af[mi] = *(const short8*)&As[buf][r * BK + (c << 3)];
            }
#pragma unroll
            for (int ni = 0; ni < 4; ++ni) {
                const int r = wn * 64 + ni * 16 + l15;
                const int c = (ks * 4 + l4) ^ (r & 7);
                bfr[ni] = *(const short8*)&Bs[buf][r * BK + (c << 3)];
            }
#pragma unroll
            for (int mi = 0; mi < 4; ++mi)
#pragma unroll
                for (int ni = 0; ni < 4; ++ni)
                    acc[mi][ni] = __builtin_amdgcn_mfma_f32_16x16x32_bf16(
                        af[mi], bfr[ni], acc[mi][ni], 0, 0, 0);
        }
    };

    // prologue
    issue_loads(0);
    write_stage(0);
    __syncthreads();

    int cur = 0;
    for (int kt = 0; kt < NKT; ++kt) {
        if (kt + 1 < NKT) issue_loads(kt + 1);   // HBM latency hides under compute
        compute(cur);
        if (kt + 1 < NKT) write_stage(cur ^ 1);  // cvt + ds_write after loads land
        __syncthreads();
        cur ^= 1;
    }

    // epilogue: C/D layout col=lane&15, row=(lane>>4)*4+reg (m89-verified)
#pragma unroll
    for (int mi = 0; mi < 4; ++mi) {
        const int rbase = row0 + wm * 64 + mi * 16 + l4 * 4;
#pragma unroll
        for (int ni = 0; ni < 4; ++ni) {
            const int c = col0 + wn * 64 + ni * 16 + l15;
#pragma unroll
            for (int r = 0; r < 4; ++r)
                out[(size_t)(rbase + r) * Nd + c] = acc[mi][ni][r];
        }
    }
}

extern "C" void kernel_launch(void* const* d_in, const int* in_sizes, int n_in,
                              void* d_out, int out_size, void* d_ws, size_t ws_size,
                              hipStream_t stream) {
    const float* H = (const float*)d_in[0];
    const float* W = (const float*)d_in[1];
    const int* counts = (const int*)d_in[2];
    float* out = (float*)d_out;
    const int grid = (Tt / BM) * (Nd / BN);  // 64 * 8 = 512 blocks
    grouped_gemm_kernel<<<grid, 256, 0, stream>>>(H, W, counts, out);
}